// Round 10
// baseline (98.416 us; speedup 1.0000x reference)
//
#include <hip/hip_runtime.h>
#include <hip/hip_fp16.h>

// TensorFusion: out = tanh(tanh(tanh(fusion@W1+b1)@W2+b2)@W3+b3)
// fusion[b,(i,j,k)] = a_h[b,i]*v_h[b,j]*t_h[b,k], a_h=[1,a], 65^3 = 274625 cols.
// K decomposes into 4291 segments of K=64 (+ row 0 folded into tail bias).
// A[b,t] = scale[b]*inner[b,t] generated in-register (f16).
// ROUND 10: 3-SUPERPHASE deep-staged design. LDS holds 15 whole segment tiles
// (f16 [n][k], 144B row pitch + chunk rotation -> b128 frag reads at BW floor).
// Superphases {0..7},{8..14},{15,16}: stage-to-regs (16KB/wave in flight),
// cvt->LDS, ONE barrier each; next superphase's global loads are issued
// BEFORE computing the current one, so they fly under the MFMA phase.
// Only ~1 real latency exposure in the whole kernel; no inline asm.
// Grid 256 (1 block/CU), 512 thr, BM=512 -> W1 read exactly once.
// Split-K f16 partials [chunk][512][64] (dense 64KB/block) reduced in tail.

typedef _Float16 f16;
typedef f16 f16x8 __attribute__((ext_vector_type(8)));
typedef f16 f16x2 __attribute__((ext_vector_type(2)));
typedef float fx4 __attribute__((ext_vector_type(4)));

#define WS_AT    0
#define WS_VT    131072
#define WS_PART  262144   // f16 [256][512][64] = 16777216 B

__device__ __forceinline__ void seg_decode(int s, int& ia, int& iv, int& isel,
                                           int& rowbase, int& rowstride) {
  if (s < 4096)      { int i = s >> 6, j = s & 63; ia = i; iv = j; isel = 0;
                       rowbase = (i+1)*4225 + (j+1)*65 + 1; rowstride = 1; }
  else if (s < 4160) { int i = s - 4096; ia = i; iv = -1; isel = 2;
                       rowbase = (i+1)*4225 + 65; rowstride = 65; }
  else if (s < 4224) { int i = s - 4160; ia = i; iv = -1; isel = 0;
                       rowbase = (i+1)*4225 + 1; rowstride = 1; }
  else if (s < 4288) { int j = s - 4224; ia = -1; iv = j; isel = 0;
                       rowbase = (j+1)*65 + 1; rowstride = 1; }
  else if (s == 4288){ ia = -1; iv = -1; isel = 1; rowbase = 4225; rowstride = 4225; }
  else if (s == 4289){ ia = -1; iv = -1; isel = 2; rowbase = 65;   rowstride = 65; }
  else if (s == 4290){ ia = -1; iv = -1; isel = 0; rowbase = 1;    rowstride = 1; }
  else               { ia = -2; iv = -1; isel = 0; rowbase = 1;    rowstride = 1; } // dummy: scale 0
}

__device__ __forceinline__ f16x8 cvt8(fx4 x0, fx4 x1) {
  f16x8 f;
  f[0]=(f16)x0[0]; f[1]=(f16)x0[1]; f[2]=(f16)x0[2]; f[3]=(f16)x0[3];
  f[4]=(f16)x1[0]; f[5]=(f16)x1[1]; f[6]=(f16)x1[2]; f[7]=(f16)x1[3];
  return f;
}

// ---------------- prep: aT/vT transposes (coalesced scale loads) ----------------
__global__ __launch_bounds__(256) void prep_kernel(
    const float* __restrict__ a, const float* __restrict__ v,
    float* __restrict__ aT, float* __restrict__ vT)
{
  int g = blockIdx.x * 256 + threadIdx.x;   // 2*32768 items
  int which = g >> 15;
  int idx = g & 32767;
  if (which == 0) aT[idx] = a[((idx & 511) << 6) + (idx >> 9)];  // aT[c][r]=a[r][c]
  else            vT[idx] = v[((idx & 511) << 6) + (idx >> 9)];
}

// compute one segment from its LDS tile
__device__ __forceinline__ void compute_seg(
    int t, int segbase, const f16* __restrict__ buf,
    const f16 (* __restrict__ pl_all)[512],
    const f16x8 (&lfrag)[4][2],
    const float* __restrict__ a, const float* __restrict__ v,
    int wave, int l15, int l4, fx4 (&acc)[4][4])
{
  int s = segbase + t;
  int isel = ((s >= 4096 && s < 4160) || s == 4289) ? 2 : (s == 4288 ? 1 : 0);
  #pragma unroll
  for (int ks = 0; ks < 2; ++ks) {
    f16x8 bf[4];
    #pragma unroll
    for (int nt = 0; nt < 4; ++nt) {
      int n = (nt << 4) + l15;
      int c2 = (((ks << 2) + l4) + (n >> 3)) & 7;        // chunk rotation
      bf[nt] = *(const f16x8*)((const char*)buf + n * 144 + (c2 << 4));
    }
    #pragma unroll
    for (int mt = 0; mt < 4; ++mt) {
      int lrow = (wave << 6) + (mt << 4) + l15;
      f16 ps = pl_all[t][lrow];
      f16x8 lv;
      if (isel == 0) lv = lfrag[mt][ks];
      else {
        const float* p = (isel == 1 ? a : v) + ((size_t)lrow << 6) + (ks << 5) + (l4 << 3);
        lv = cvt8(*(const fx4*)p, *(const fx4*)(p + 4));
      }
      f16x2 ps2 = { ps, ps };
      f16x8 av;
      ((f16x2*)&av)[0] = ((f16x2*)&lv)[0] * ps2;
      ((f16x2*)&av)[1] = ((f16x2*)&lv)[1] * ps2;
      ((f16x2*)&av)[2] = ((f16x2*)&lv)[2] * ps2;
      ((f16x2*)&av)[3] = ((f16x2*)&lv)[3] * ps2;
      #pragma unroll
      for (int nt = 0; nt < 4; ++nt)
        acc[mt][nt] = __builtin_amdgcn_mfma_f32_16x16x32_f16(av, bf[nt], acc[mt][nt], 0, 0, 0);
    }
  }
}

// ---------------- stage 1: the big implicit GEMM ----------------
__global__ __launch_bounds__(512, 2) void fusion_gemm(
    const float* __restrict__ W1,
    const float* __restrict__ aT, const float* __restrict__ vT,
    const float* __restrict__ a, const float* __restrict__ v, const float* __restrict__ l,
    f16* __restrict__ partials)
{
  __shared__ f16 bufs[15][4608];      // 15 seg tiles, [n][k] f16, 144B row pitch
  __shared__ f16 pl_all[17][512];     // per-seg per-row scales

  const int tid  = threadIdx.x;       // 0..511
  const int chunk= blockIdx.x;        // 0..255
  const int lane = tid & 63;
  const int wave = tid >> 6;          // 0..7
  const int l15  = lane & 15;
  const int l4   = lane >> 4;
  const int segbase = chunk * 17;     // 256*17 = 4352 >= 4291
  const int kst  = tid >> 3;          // staging: k-row 0..63
  const int ngst = tid & 7;           // staging: n-octet

  fx4 st[8][2];                       // staging regs: 8 segs x 8 dwords

#define ISSUE(J, T) do {                                                      \
    int s_ = segbase + (T), ia_, iv_, is_, rb_, rs_;                          \
    seg_decode(s_, ia_, iv_, is_, rb_, rs_);                                  \
    const float* g_ = W1 + (size_t)(rb_ + kst * rs_) * 64 + (ngst << 3);      \
    st[J][0] = *(const fx4*)g_;                                               \
    st[J][1] = *(const fx4*)(g_ + 4);                                         \
  } while (0)

  // write staged seg J -> LDS buf (cvt f16; rotated chunk layout)
#define WRITESEG(J, BUF) do {                                                 \
    int c2_ = ((kst >> 3) + ngst) & 7;                                        \
    char* base_ = (char*)&bufs[BUF][0] + (size_t)(ngst << 3) * 144            \
                  + (c2_ << 4) + ((kst & 7) << 1);                            \
    _Pragma("unroll")                                                         \
    for (int e_ = 0; e_ < 8; ++e_)                                            \
      *(f16*)(base_ + e_ * 144) = (f16)st[J][e_ >> 2][e_ & 3];                \
  } while (0)

  // ---- prologue: superphase-0 loads in flight FIRST ----
  ISSUE(0, 0); ISSUE(1, 1); ISSUE(2, 2); ISSUE(3, 3);
  ISSUE(4, 4); ISSUE(5, 5); ISSUE(6, 6); ISSUE(7, 7);

  // scales (34 coalesced loads, overlap the W1 loads)
  #pragma unroll
  for (int t = 0; t < 17; ++t) {
    int s = segbase + t, ia, iv, is_, rb, rs;
    seg_decode(s, ia, iv, is_, rb, rs);
    float spa = (ia >= 0) ? aT[(ia << 9) + tid] : (ia == -1 ? 1.0f : 0.0f);
    float spv = (iv >= 0) ? vT[(iv << 9) + tid] : 1.0f;
    pl_all[t][tid] = (f16)(spa * spv);
  }

  // A-operand (l) fragments
  f16x8 lfrag[4][2];
  #pragma unroll
  for (int mt = 0; mt < 4; ++mt) {
    int row = (wave << 6) + (mt << 4) + l15;
    #pragma unroll
    for (int ks = 0; ks < 2; ++ks) {
      const float* p = l + ((size_t)row << 6) + (ks << 5) + (l4 << 3);
      lfrag[mt][ks] = cvt8(*(const fx4*)p, *(const fx4*)(p + 4));
    }
  }

  fx4 acc[4][4] = {};

  WRITESEG(0, 0); WRITESEG(1, 1); WRITESEG(2, 2); WRITESEG(3, 3);
  WRITESEG(4, 4); WRITESEG(5, 5); WRITESEG(6, 6); WRITESEG(7, 7);
  __syncthreads();                    // exposure #1 (the only real one)

  // ---- superphase 0: issue sp1, compute segs 0-7, write sp1 ----
  ISSUE(0, 8); ISSUE(1, 9); ISSUE(2, 10); ISSUE(3, 11);
  ISSUE(4, 12); ISSUE(5, 13); ISSUE(6, 14);
  #pragma unroll 1
  for (int t = 0; t < 8; ++t)
    compute_seg(t, segbase, &bufs[t][0], pl_all, lfrag, a, v, wave, l15, l4, acc);
  WRITESEG(0, 8); WRITESEG(1, 9); WRITESEG(2, 10); WRITESEG(3, 11);
  WRITESEG(4, 12); WRITESEG(5, 13); WRITESEG(6, 14);
  __syncthreads();

  // ---- superphase 1: issue sp2, compute segs 8-14, write sp2 (bufs 0,1) ----
  ISSUE(0, 15); ISSUE(1, 16);
  #pragma unroll 1
  for (int t = 8; t < 15; ++t)
    compute_seg(t, segbase, &bufs[t][0], pl_all, lfrag, a, v, wave, l15, l4, acc);
  WRITESEG(0, 0); WRITESEG(1, 1);
  __syncthreads();

  // ---- superphase 2: compute segs 15,16 ----
  compute_seg(15, segbase, &bufs[0][0], pl_all, lfrag, a, v, wave, l15, l4, acc);
  compute_seg(16, segbase, &bufs[1][0], pl_all, lfrag, a, v, wave, l15, l4, acc);
#undef ISSUE
#undef WRITESEG

  // ---- epilogue: dense 64KB block write via LDS transpose ----
  __syncthreads();
  f16* eb = &bufs[0][0];              // reuse as f16 [512][64]
  #pragma unroll
  for (int mt = 0; mt < 4; ++mt)
    #pragma unroll
    for (int nt = 0; nt < 4; ++nt)
      #pragma unroll
      for (int r = 0; r < 4; ++r) {
        int lrow = (wave << 6) + (mt << 4) + (l4 << 2) + r;
        int n = (nt << 4) + l15;
        eb[(lrow << 6) + n] = (f16)acc[mt][nt][r];
      }
  __syncthreads();
  {
    f16* gbase = partials + ((size_t)chunk << 15);   // 32768 f16 per chunk
    #pragma unroll
    for (int j = 0; j < 8; ++j) {
      int c = (j << 9) + tid;         // 16-B piece id 0..4095
      *(f16x8*)(gbase + ((size_t)c << 3)) = *(const f16x8*)(eb + (c << 3));
    }
  }
}

// ---------------- tail: reduce partials + bias + tanh + 2x 64x64 GEMM ----------------
__global__ __launch_bounds__(256) void tail_kernel(
    const f16* __restrict__ partials, const float* __restrict__ W1, const float* __restrict__ b1,
    const float* __restrict__ W2, const float* __restrict__ b2,
    const float* __restrict__ W3, const float* __restrict__ b3, float* __restrict__ out)
{
  __shared__ float red[4][64];
  __shared__ float hbuf[64];
  __shared__ float h2buf[64];
  const int row = blockIdx.x;          // 0..511
  const int t = threadIdx.x;
  const int q = t >> 6, n = t & 63;
  // partials element (chunk, row, n) at chunk*32768 + row*64 + n
  const f16* base = partials + ((size_t)row << 6) + n;

  float s0 = 0.f, s1 = 0.f, s2 = 0.f, s3 = 0.f;
  #pragma unroll 4
  for (int c = q; c < 256; c += 16) {
    s0 += (float)base[(size_t)c << 15];
    s1 += (float)base[(size_t)(c + 4) << 15];
    s2 += (float)base[(size_t)(c + 8) << 15];
    s3 += (float)base[(size_t)(c + 12) << 15];
  }
  red[q][n] = (s0 + s1) + (s2 + s3);
  __syncthreads();
  if (t < 64) {
    float acc = b1[t] + W1[t] + red[0][t] + red[1][t] + red[2][t] + red[3][t];
    hbuf[t] = tanhf(acc);              // W1[t] = row-0 (1*1*1) term
  }
  __syncthreads();
  if (t < 64) {
    float acc = b2[t];
    #pragma unroll 8
    for (int k = 0; k < 64; ++k) acc += hbuf[k] * W2[(k << 6) + t];
    h2buf[t] = tanhf(acc);
  }
  __syncthreads();
  if (t < 64) {
    float acc = b3[t];
    #pragma unroll 8
    for (int k = 0; k < 64; ++k) acc += h2buf[k] * W3[(k << 6) + t];
    out[(row << 6) + t] = tanhf(acc);
  }
}

extern "C" void kernel_launch(void* const* d_in, const int* in_sizes, int n_in,
                              void* d_out, int out_size, void* d_ws, size_t ws_size,
                              hipStream_t stream) {
  const float* l  = (const float*)d_in[0];
  const float* a  = (const float*)d_in[1];
  const float* v  = (const float*)d_in[2];
  const float* W1 = (const float*)d_in[3];
  const float* b1 = (const float*)d_in[4];
  const float* W2 = (const float*)d_in[5];
  const float* b2 = (const float*)d_in[6];
  const float* W3 = (const float*)d_in[7];
  const float* b3 = (const float*)d_in[8];
  float* out = (float*)d_out;

  char* ws = (char*)d_ws;
  float* aT = (float*)(ws + WS_AT);
  float* vT = (float*)(ws + WS_VT);
  f16* partials = (f16*)(ws + WS_PART);

  hipLaunchKernelGGL(prep_kernel, dim3(256), dim3(256), 0, stream, a, v, aT, vT);
  hipLaunchKernelGGL(fusion_gemm, dim3(256), dim3(512), 0, stream,
                     W1, aT, vT, a, v, l, partials);
  hipLaunchKernelGGL(tail_kernel, dim3(512), dim3(256), 0, stream,
                     partials, W1, b1, W2, b2, W3, b3, out);
}

// Round 11
// 78.962 us; speedup vs baseline: 1.2464x; 1.2464x over previous
//
#include <hip/hip_runtime.h>
#include <hip/hip_fp16.h>

// TensorFusion: out = tanh(tanh(tanh(fusion@W1+b1)@W2+b2)@W3+b3)
// fusion[b,(i,j,k)] = a_h[b,i]*v_h[b,j]*t_h[b,k], a_h=[1,a], 65^3 = 274625 cols.
// K decomposes into 4291 segments of K=64 (+ row 0 folded into tail bias).
// A[b,t] = scale[b]*inner[b,t] generated in-register (f16).
// ROUND 11: r7-fixed. 1-wave blocks (64 thr), launch_bounds(64,2) -> 256 VGPR
// cap, 8 free-running blocks/CU, NO inter-wave coupling. Per segment each wave
// stages the 64x64 W1 tile into 64 regs (strided dword loads, L1 dedup),
// cvt->f16 (frees regs), issues seg t+1's loads BEFORE the 32 MFMAs
// (sched_barrier pin). Latency hidden by 8-way block TLP (m114), not barriers.
// Grid 2048 = 8 M-tiles x 256 K-chunks; bid%8=chunk%8 -> M-siblings same XCD.
// Split-K f16 partials [chunk][512][64] (dense 8KB/block) reduced in tail.

typedef _Float16 f16;
typedef f16 f16x8 __attribute__((ext_vector_type(8)));
typedef f16 f16x2 __attribute__((ext_vector_type(2)));
typedef __fp16 fp16x2 __attribute__((ext_vector_type(2)));
typedef float fx4 __attribute__((ext_vector_type(4)));

#define WS_AT    0
#define WS_VT    131072
#define WS_PART  262144   // f16 [256][512][64] = 16777216 B

__device__ __forceinline__ f16x2 pkrtz(float a, float b) {
  fp16x2 r = __builtin_amdgcn_cvt_pkrtz(a, b);
  return *(f16x2*)&r;
}

__device__ __forceinline__ void seg_decode(int s, int& ia, int& iv, int& isel,
                                           int& rowbase, int& rowstride) {
  if (s < 4096)      { int i = s >> 6, j = s & 63; ia = i; iv = j; isel = 0;
                       rowbase = (i+1)*4225 + (j+1)*65 + 1; rowstride = 1; }
  else if (s < 4160) { int i = s - 4096; ia = i; iv = -1; isel = 2;
                       rowbase = (i+1)*4225 + 65; rowstride = 65; }
  else if (s < 4224) { int i = s - 4160; ia = i; iv = -1; isel = 0;
                       rowbase = (i+1)*4225 + 1; rowstride = 1; }
  else if (s < 4288) { int j = s - 4224; ia = -1; iv = j; isel = 0;
                       rowbase = (j+1)*65 + 1; rowstride = 1; }
  else if (s == 4288){ ia = -1; iv = -1; isel = 1; rowbase = 4225; rowstride = 4225; }
  else if (s == 4289){ ia = -1; iv = -1; isel = 2; rowbase = 65;   rowstride = 65; }
  else if (s == 4290){ ia = -1; iv = -1; isel = 0; rowbase = 1;    rowstride = 1; }
  else               { ia = -2; iv = -1; isel = 0; rowbase = 1;    rowstride = 1; } // dummy: scale 0
}

__device__ __forceinline__ f16x8 cvt8(fx4 x0, fx4 x1) {
  f16x8 f;
  f[0]=(f16)x0[0]; f[1]=(f16)x0[1]; f[2]=(f16)x0[2]; f[3]=(f16)x0[3];
  f[4]=(f16)x1[0]; f[5]=(f16)x1[1]; f[6]=(f16)x1[2]; f[7]=(f16)x1[3];
  return f;
}

// ---------------- prep: aT/vT transposes (coalesced scale loads) ----------------
__global__ __launch_bounds__(256) void prep_kernel(
    const float* __restrict__ a, const float* __restrict__ v,
    float* __restrict__ aT, float* __restrict__ vT)
{
  int g = blockIdx.x * 256 + threadIdx.x;   // 2*32768 items
  int which = g >> 15;
  int idx = g & 32767;
  if (which == 0) aT[idx] = a[((idx & 511) << 6) + (idx >> 9)];  // aT[c][r]=a[r][c]
  else            vT[idx] = v[((idx & 511) << 6) + (idx >> 9)];
}

// ---------------- stage 1: the big implicit GEMM (1 wave per block) ----------------
__global__ __launch_bounds__(64, 2) void fusion_gemm(
    const float* __restrict__ W1,
    const float* __restrict__ aT, const float* __restrict__ vT,
    const float* __restrict__ a, const float* __restrict__ v, const float* __restrict__ l,
    f16* __restrict__ partials)
{
  __shared__ f16 pl_all[17][64];      // per-seg per-row scales (2.2 KB)
  __shared__ f16 eb[64 * 64];         // epilogue staging (8 KB)

  const int lane = threadIdx.x;       // 0..63
  const int bid  = blockIdx.x;        // 0..2047
  const int cLo  = bid & 7;           // XCD slot == chunk low bits
  const int q    = bid >> 3;
  const int mtile= q & 7;             // 0..7 M-tile (64 rows)
  const int chunk= ((q >> 3) << 3) | cLo;   // 0..255
  const int l15  = lane & 15;
  const int l4   = lane >> 4;         // 0..3
  const int segbase = chunk * 17;     // 256*17 = 4352 >= 4291
  const int row0 = mtile << 6;

  // ---- scales: pl_all[t][r] (coalesced 64-wide) ----
  #pragma unroll
  for (int t = 0; t < 17; ++t) {
    int s = segbase + t, ia, iv, is_, rb, rs;
    seg_decode(s, ia, iv, is_, rb, rs);
    float spa = (ia >= 0) ? aT[(ia << 9) + row0 + lane] : (ia == -1 ? 1.0f : 0.0f);
    float spv = (iv >= 0) ? vT[(iv << 9) + row0 + lane] : 1.0f;
    pl_all[t][lane] = (f16)(spa * spv);
  }

  // ---- A-operand (l) fragments: rows row0 + mt*16 + l15 ----
  f16x8 lfrag[4][2];
  #pragma unroll
  for (int mt = 0; mt < 4; ++mt) {
    int row = row0 + (mt << 4) + l15;
    #pragma unroll
    for (int ks = 0; ks < 2; ++ks) {
      const float* p = l + ((size_t)row << 6) + (ks << 5) + (l4 << 3);
      lfrag[mt][ks] = cvt8(*(const fx4*)p, *(const fx4*)(p + 4));
    }
  }

  fx4 acc[4][4] = {};                 // 64 VGPRs
  float w[2][4][8];                   // 64 VGPRs staging (single buffer)
  f16x8 bf[2][4];                     // 32 VGPRs current-seg B-frags

  __syncthreads();                    // trivial (1 wave); pl_all ordering

  // w[ks][nt][e] = W1[rb + (ks*32 + l4*8 + e)*rs][nt*16 + l15]
#define ISSUE(T) do {                                                         \
    int s_ = segbase + (T), ia_, iv_, is_, rb_, rs_;                          \
    seg_decode(s_, ia_, iv_, is_, rb_, rs_);                                  \
    const int rstep_ = rs_ << 6;                                              \
    const float* b_ = W1 + (size_t)rb_ * 64 + (size_t)((l4 << 3) * rstep_) + l15; \
    _Pragma("unroll")                                                         \
    for (int ks_ = 0; ks_ < 2; ++ks_)                                         \
      _Pragma("unroll")                                                       \
      for (int nt_ = 0; nt_ < 4; ++nt_) {                                     \
        const float* p_ = b_ + (size_t)((ks_ << 5) * rstep_) + (nt_ << 4);    \
        _Pragma("unroll")                                                     \
        for (int e_ = 0; e_ < 8; ++e_)                                        \
          w[ks_][nt_][e_] = p_[(size_t)(e_ * rstep_)];                        \
      }                                                                       \
  } while (0)

  ISSUE(0);

  #pragma unroll 1
  for (int t = 0; t < 17; ++t) {
    // cvt staged seg t (vmcnt wait lands here), freeing w
    #pragma unroll
    for (int ks = 0; ks < 2; ++ks)
      #pragma unroll
      for (int nt = 0; nt < 4; ++nt) {
        ((f16x2*)&bf[ks][nt])[0] = pkrtz(w[ks][nt][0], w[ks][nt][1]);
        ((f16x2*)&bf[ks][nt])[1] = pkrtz(w[ks][nt][2], w[ks][nt][3]);
        ((f16x2*)&bf[ks][nt])[2] = pkrtz(w[ks][nt][4], w[ks][nt][5]);
        ((f16x2*)&bf[ks][nt])[3] = pkrtz(w[ks][nt][6], w[ks][nt][7]);
      }
    if (t + 1 < 17) ISSUE(t + 1);     // next seg's 64 loads fly under the MFMAs
    __builtin_amdgcn_sched_barrier(0); // pin: loads stay above the MFMA cluster

    int s = segbase + t;
    int isel = ((s >= 4096 && s < 4160) || s == 4289) ? 2 : (s == 4288 ? 1 : 0);
    #pragma unroll
    for (int ks = 0; ks < 2; ++ks)
      #pragma unroll
      for (int mt = 0; mt < 4; ++mt) {
        f16 ps = pl_all[t][(mt << 4) + l15];
        f16x8 lv;
        if (isel == 0) lv = lfrag[mt][ks];
        else {
          const float* p = (isel == 1 ? a : v)
              + ((size_t)(row0 + (mt << 4) + l15) << 6) + (ks << 5) + (l4 << 3);
          lv = cvt8(*(const fx4*)p, *(const fx4*)(p + 4));
        }
        f16x2 ps2 = { ps, ps };
        f16x8 av;
        ((f16x2*)&av)[0] = ((f16x2*)&lv)[0] * ps2;
        ((f16x2*)&av)[1] = ((f16x2*)&lv)[1] * ps2;
        ((f16x2*)&av)[2] = ((f16x2*)&lv)[2] * ps2;
        ((f16x2*)&av)[3] = ((f16x2*)&lv)[3] * ps2;
        #pragma unroll
        for (int nt = 0; nt < 4; ++nt)
          acc[mt][nt] = __builtin_amdgcn_mfma_f32_16x16x32_f16(av, bf[ks][nt], acc[mt][nt], 0, 0, 0);
      }
  }
#undef ISSUE

  // ---- epilogue: dense 8KB write via LDS transpose (1 wave, no barrier) ----
  #pragma unroll
  for (int mt = 0; mt < 4; ++mt)
    #pragma unroll
    for (int nt = 0; nt < 4; ++nt)
      #pragma unroll
      for (int r = 0; r < 4; ++r) {
        int lrow = (mt << 4) + (l4 << 2) + r;
        eb[(lrow << 6) + (nt << 4) + l15] = (f16)acc[mt][nt][r];
      }
  __syncthreads();                    // 1-wave: cheap; orders LDS writes->reads
  {
    f16* gbase = partials + ((size_t)chunk << 15) + ((size_t)row0 << 6);
    #pragma unroll
    for (int j = 0; j < 8; ++j) {
      int c = (j << 6) + lane;        // 16-B piece 0..511
      *(f16x8*)(gbase + (c << 3)) = *(const f16x8*)(eb + (c << 3));
    }
  }
}

// ---------------- tail: reduce partials + bias + tanh + 2x 64x64 GEMM ----------------
__global__ __launch_bounds__(256) void tail_kernel(
    const f16* __restrict__ partials, const float* __restrict__ W1, const float* __restrict__ b1,
    const float* __restrict__ W2, const float* __restrict__ b2,
    const float* __restrict__ W3, const float* __restrict__ b3, float* __restrict__ out)
{
  __shared__ float red[4][64];
  __shared__ float hbuf[64];
  __shared__ float h2buf[64];
  const int row = blockIdx.x;          // 0..511
  const int t = threadIdx.x;
  const int q = t >> 6, n = t & 63;
  // partials element (chunk, row, n) at chunk*32768 + row*64 + n
  const f16* base = partials + ((size_t)row << 6) + n;

  float s0 = 0.f, s1 = 0.f, s2 = 0.f, s3 = 0.f;
  #pragma unroll 4
  for (int c = q; c < 256; c += 16) {
    s0 += (float)base[(size_t)c << 15];
    s1 += (float)base[(size_t)(c + 4) << 15];
    s2 += (float)base[(size_t)(c + 8) << 15];
    s3 += (float)base[(size_t)(c + 12) << 15];
  }
  red[q][n] = (s0 + s1) + (s2 + s3);
  __syncthreads();
  if (t < 64) {
    float acc = b1[t] + W1[t] + red[0][t] + red[1][t] + red[2][t] + red[3][t];
    hbuf[t] = tanhf(acc);              // W1[t] = row-0 (1*1*1) term
  }
  __syncthreads();
  if (t < 64) {
    float acc = b2[t];
    #pragma unroll 8
    for (int k = 0; k < 64; ++k) acc += hbuf[k] * W2[(k << 6) + t];
    h2buf[t] = tanhf(acc);
  }
  __syncthreads();
  if (t < 64) {
    float acc = b3[t];
    #pragma unroll 8
    for (int k = 0; k < 64; ++k) acc += h2buf[k] * W3[(k << 6) + t];
    out[(row << 6) + t] = tanhf(acc);
  }
}

extern "C" void kernel_launch(void* const* d_in, const int* in_sizes, int n_in,
                              void* d_out, int out_size, void* d_ws, size_t ws_size,
                              hipStream_t stream) {
  const float* l  = (const float*)d_in[0];
  const float* a  = (const float*)d_in[1];
  const float* v  = (const float*)d_in[2];
  const float* W1 = (const float*)d_in[3];
  const float* b1 = (const float*)d_in[4];
  const float* W2 = (const float*)d_in[5];
  const float* b2 = (const float*)d_in[6];
  const float* W3 = (const float*)d_in[7];
  const float* b3 = (const float*)d_in[8];
  float* out = (float*)d_out;

  char* ws = (char*)d_ws;
  float* aT = (float*)(ws + WS_AT);
  float* vT = (float*)(ws + WS_VT);
  f16* partials = (f16*)(ws + WS_PART);

  hipLaunchKernelGGL(prep_kernel, dim3(256), dim3(256), 0, stream, a, v, aT, vT);
  hipLaunchKernelGGL(fusion_gemm, dim3(2048), dim3(64), 0, stream,
                     W1, aT, vT, a, v, l, partials);
  hipLaunchKernelGGL(tail_kernel, dim3(512), dim3(256), 0, stream,
                     partials, W1, b1, W2, b2, W3, b3, out);
}